// Round 1
// 2061.270 us; speedup vs baseline: 1.1161x; 1.1161x over previous
//
#include <hip/hip_runtime.h>
#include <cstdint>
#include <cstddef>

typedef unsigned short u16;
typedef __attribute__((ext_vector_type(8))) short short8;
typedef __attribute__((ext_vector_type(4))) float f32x4;

#define XT_HSTRIDE 18432      /* 2*36*256 */
#define XT_BSTRIDE 1308672    /* 71*18432 */
#define K_TOT 20736
#define N_TOT 32768

__device__ __forceinline__ u16 f2bf(float f) {
  uint32_t u = __builtin_bit_cast(uint32_t, f);
  u = (u + 0x7fffu + ((u >> 16) & 1u)) >> 16;
  return (u16)u;
}
__device__ __forceinline__ float bf2f(u16 h) {
  uint32_t u = ((uint32_t)h) << 16;
  return __builtin_bit_cast(float, u);
}

// async global->LDS, 16B per lane; LDS dest is wave-uniform base + lane*16
__device__ __forceinline__ void gl_lds16(const u16* g, u16* l) {
  __builtin_amdgcn_global_load_lds((const __attribute__((address_space(1))) void*)g,
                                   (__attribute__((address_space(3))) void*)l, 16, 0, 0);
}

// ---- pack weights: Wb[m][pos*256+c] = bf16(W[m][c][kh][kw]) ----
__global__ __launch_bounds__(256) void pack_w(const float* __restrict__ W,
                                              u16* __restrict__ Wb) {
  __shared__ u16 wl[20736];
  const int m = blockIdx.x;
  const int t = threadIdx.x;
  const size_t base = (size_t)m * K_TOT;
  for (int i = t; i < K_TOT; i += 256) {
    float f = W[base + i];          // input layout per m: (c, pos), i = c*81+pos
    int c = i / 81;
    int pos = i - c * 81;
    wl[pos * 256 + c] = f2bf(f);
  }
  __syncthreads();
  for (int i = t; i < K_TOT; i += 256) Wb[base + i] = wl[i];
}

// ---- pack x: xT[b][h][par][j][c] = bf16(x[b][c][h][2j+par]) ----
__global__ __launch_bounds__(256) void pack_x(const float* __restrict__ X,
                                              u16* __restrict__ xT) {
  __shared__ u16 xl[256 * 73];
  const int h = blockIdx.x;   // 0..70
  const int b = blockIdx.y;   // 0..31
  const int t = threadIdx.x;  // = c on write phase
  for (int i = t; i < 256 * 71; i += 256) {
    int c = i / 71;
    int w = i - c * 71;
    float f = X[(((size_t)(b * 256 + c)) * 71 + h) * 71 + w];
    xl[c * 73 + w] = f2bf(f);
  }
  __syncthreads();
  const size_t obase = (size_t)b * XT_BSTRIDE + (size_t)h * XT_HSTRIDE;
  for (int s = 0; s < 71; ++s) {
    int par = (s >= 36) ? 1 : 0;
    int j = s - par * 36;
    int w = 2 * j + par;
    xT[obase + par * 9216 + j * 256 + t] = xl[t * 73 + w];
  }
}

// ---- conv as implicit GEMM: U[m][n] = sum_k Wb[m][k] * X[n][k] ----
// n = b*1024 + hp*32 + wp ; k = (kh*9+kw)*256 + c
// BK=64 (128B rows). LDS tiles XOR-swizzled: LDS(row, p) holds global 16B-chunk
// p ^ (row&7). Staged via global_load_lds (lane-linear dest) with the inverse
// permutation pre-applied to the per-lane GLOBAL source address (rule 21).
__global__ __launch_bounds__(256) void conv_gemm(const u16* __restrict__ Wb,
                                                 const u16* __restrict__ xT,
                                                 u16* __restrict__ U) {
  __shared__ __align__(16) u16 As[128 * 64];
  __shared__ __align__(16) u16 Bs[128 * 64];
  const int tid = threadIdx.x;
  const int bx = blockIdx.x;
  const int m0 = (bx & 7) * 128;    // bx&7 = m-tile: pins one A-panel per XCD
  const int n0 = (bx >> 3) * 128;
  const int lane = tid & 63;
  const int wave = tid >> 6;
  const int wm = wave >> 1;   // 0..1
  const int wn = wave & 1;    // 0..1

  // staging: issue t = wave*4+q covers rows 8t..8t+7 (1024B lane-linear).
  // lane: row_local = lane>>3, lds chunk p = lane&7, source chunk g = p ^ (row&7)
  const int rl = lane >> 3;              // 0..7
  const int gch = (lane & 7) ^ rl;       // pre-swizzled source 16B-chunk

  const u16* aSrc[4];
  const u16* bSrc[4];
#pragma unroll
  for (int q = 0; q < 4; ++q) {
    const int t = wave * 4 + q;
    const int row = 8 * t + rl;          // 0..127
    aSrc[q] = Wb + (size_t)(m0 + row) * K_TOT + gch * 8;
    const int n = n0 + row;
    const size_t nb = (size_t)(n >> 10) * XT_BSTRIDE +
                      (size_t)(((n >> 5) & 31) * 2) * XT_HSTRIDE +
                      (size_t)(n & 31) * 256;
    bSrc[q] = xT + nb + gch * 8;
  }

  f32x4 acc[4][4];
#pragma unroll
  for (int i = 0; i < 4; ++i)
#pragma unroll
    for (int j = 0; j < 4; ++j) acc[i][j] = (f32x4){0.f, 0.f, 0.f, 0.f};

  // fragment ds_read byte offsets: row r, logical chunk cl=h*4+quad ->
  // byte = r*128 + ((cl ^ (r&7)))*16 ; (r&7)==(fr&7) since wm*64+i*16 is mult of 8
  const int q4 = lane >> 4;      // 0..3
  const int fr = lane & 15;      // row within 16-row fragment
  uint32_t aOff[4][2], bOff[4][2];
#pragma unroll
  for (int i = 0; i < 4; ++i) {
#pragma unroll
    for (int h = 0; h < 2; ++h) {
      const int ra = wm * 64 + i * 16 + fr;
      const int rb = wn * 64 + i * 16 + fr;
      const int sc = (h * 4 + q4) ^ (fr & 7);
      aOff[i][h] = (uint32_t)(ra * 128 + sc * 16);
      bOff[i][h] = (uint32_t)(rb * 128 + sc * 16);
    }
  }

  for (int kh = 0; kh < 9; ++kh) {
    for (int kw = 0; kw < 9; ++kw) {
      const int koffA = (kh * 9 + kw) * 256;
      const int koffB = kh * XT_HSTRIDE + (kw & 1) * 9216 + (kw >> 1) * 256;
      for (int c0 = 0; c0 < 256; c0 += 64) {
        __syncthreads();   // previous iter's ds_reads done -> safe to overwrite
#pragma unroll
        for (int q = 0; q < 4; ++q) {
          gl_lds16(aSrc[q] + koffA + c0, As + (wave * 4 + q) * 512);
          gl_lds16(bSrc[q] + koffB + c0, Bs + (wave * 4 + q) * 512);
        }
        __syncthreads();   // vmcnt(0) drain: tiles visible to all waves

        short8 a0[4], b0[4], a1[4], b1[4];
#pragma unroll
        for (int i = 0; i < 4; ++i) {
          a0[i] = *(const short8*)((const char*)As + aOff[i][0]);
          b0[i] = *(const short8*)((const char*)Bs + bOff[i][0]);
          a1[i] = *(const short8*)((const char*)As + aOff[i][1]);
          b1[i] = *(const short8*)((const char*)Bs + bOff[i][1]);
        }
#pragma unroll
        for (int i = 0; i < 4; ++i)
#pragma unroll
          for (int j = 0; j < 4; ++j) {
            acc[i][j] = __builtin_amdgcn_mfma_f32_16x16x32_bf16(a0[i], b0[j], acc[i][j], 0, 0, 0);
            acc[i][j] = __builtin_amdgcn_mfma_f32_16x16x32_bf16(a1[i], b1[j], acc[i][j], 0, 0, 0);
          }
      }
    }
  }

  // C/D layout: col = lane&15, row = (lane>>4)*4 + reg   [measured m89/m91]
  const int r0 = (lane >> 4) * 4;
  const int cn = lane & 15;
#pragma unroll
  for (int i = 0; i < 4; ++i) {
#pragma unroll
    for (int j = 0; j < 4; ++j) {
      const int mg = m0 + wm * 64 + i * 16 + r0;
      const int ng = n0 + wn * 64 + j * 16 + cn;
#pragma unroll
      for (int r = 0; r < 4; ++r)
        U[(size_t)(mg + r) * N_TOT + ng] = f2bf(acc[i][j][r]);
    }
  }
}

// ---- dynamic routing: one block per (b,hp); thread = (nc,oc) ----
__global__ __launch_bounds__(1024) void routing_k(const u16* __restrict__ U,
                                                  const float* __restrict__ bias,
                                                  float* __restrict__ out) {
  const int t = threadIdx.x;       // m = nc*32 + oc
  const int bx = blockIdx.x;
  const int b = bx >> 5;
  const int hp = bx & 31;
  const int oc = t & 31;
  const int nc = t >> 5;
  __shared__ float sm[1024];

  float u_r[32];
  {
    const uint4* up4 = (const uint4*)(U + (size_t)t * N_TOT + b * 1024 + hp * 32);
    const float bs = bias[t];
#pragma unroll
    for (int i = 0; i < 4; ++i) {
      uint4 q = up4[i];
      uint32_t vv[4] = {q.x, q.y, q.z, q.w};
#pragma unroll
      for (int k = 0; k < 4; ++k) {
        u_r[i * 8 + k * 2]     = bf2f((u16)(vv[k] & 0xffffu)) + bs;
        u_r[i * 8 + k * 2 + 1] = bf2f((u16)(vv[k] >> 16)) + bs;
      }
    }
  }

  float bij = 0.f;
  float s[32];
  float scale = 0.f;

  for (int it = 0; it < 3; ++it) {
    sm[t] = bij;
    __syncthreads();
    // softmax over nc for this oc (values are small; no max-subtract needed)
    float den = 0.f;
#pragma unroll
    for (int i = 0; i < 32; ++i) den += __expf(sm[i * 32 + oc]);
    const float c = __expf(bij) / den;
    // s[nc][wp] = sum_oc c*u_hat : butterfly allreduce across the 32-lane oc group
#pragma unroll
    for (int w = 0; w < 32; ++w) s[w] = c * u_r[w];
#pragma unroll
    for (int off = 1; off < 32; off <<= 1) {
#pragma unroll
      for (int w = 0; w < 32; ++w) s[w] += __shfl_xor(s[w], off, 64);
    }
    // squash over wp
    float n2 = 0.f;
#pragma unroll
    for (int w = 0; w < 32; ++w) n2 += s[w] * s[w];
    scale = sqrtf(n2) / (1.f + n2);
    if (it < 2) {
      // b_ij += sum_wp u_hat * v ;  v = scale*s
      float agr = 0.f;
#pragma unroll
      for (int w = 0; w < 32; ++w) agr += u_r[w] * s[w];
      bij += scale * agr;
    }
    __syncthreads();
  }

  // lane oc writes element wp==oc (register-select to avoid scratch)
  float val = s[0];
#pragma unroll
  for (int i = 1; i < 32; ++i) val = (oc == i) ? s[i] : val;
  out[(size_t)((b * 32 + nc) * 32 + hp) * 32 + oc] = scale * val;
}

extern "C" void kernel_launch(void* const* d_in, const int* in_sizes, int n_in,
                              void* d_out, int out_size, void* d_ws, size_t ws_size,
                              hipStream_t stream) {
  const float* x = (const float*)d_in[0];
  const float* W = (const float*)d_in[1];
  const float* bias = (const float*)d_in[2];

  // workspace layout (bytes): Wb 42,467,328 | xT 83,755,008 | U 67,108,864  (total 193.3 MB)
  u16* Wb = (u16*)d_ws;
  u16* xT = (u16*)((char*)d_ws + 42467328u);
  u16* U  = (u16*)((char*)d_ws + 126222336u);
  float* out = (float*)d_out;

  pack_w<<<dim3(1024), dim3(256), 0, stream>>>(W, Wb);
  pack_x<<<dim3(71, 32), dim3(256), 0, stream>>>(x, xT);
  conv_gemm<<<dim3(2048), dim3(256), 0, stream>>>(Wb, xT, U);
  routing_k<<<dim3(1024), dim3(1024), 0, stream>>>(U, bias, out);
}

// Round 2
// 1607.170 us; speedup vs baseline: 1.4315x; 1.2825x over previous
//
#include <hip/hip_runtime.h>
#include <cstdint>
#include <cstddef>

typedef unsigned short u16;
typedef __attribute__((ext_vector_type(8))) short short8;
typedef __attribute__((ext_vector_type(4))) float f32x4;

#define XT_HSTRIDE 18432      /* 2*36*256 */
#define XT_BSTRIDE 1308672    /* 71*18432 */
#define K_TOT 20736
#define N_TOT 32768
#define NKT 324               /* K-tiles of 64: 81 pos * 4 */

__device__ __forceinline__ u16 f2bf(float f) {
  uint32_t u = __builtin_bit_cast(uint32_t, f);
  u = (u + 0x7fffu + ((u >> 16) & 1u)) >> 16;
  return (u16)u;
}
__device__ __forceinline__ float bf2f(u16 h) {
  uint32_t u = ((uint32_t)h) << 16;
  return __builtin_bit_cast(float, u);
}

// async global->LDS, 16B per lane; LDS dest is wave-uniform base + lane*16
__device__ __forceinline__ void gl_lds16(const u16* g, u16* l) {
  __builtin_amdgcn_global_load_lds((const __attribute__((address_space(1))) void*)g,
                                   (__attribute__((address_space(3))) void*)l, 16, 0, 0);
}

__device__ __forceinline__ void wg_barrier() {
  asm volatile("" ::: "memory");
  __builtin_amdgcn_s_barrier();
  asm volatile("" ::: "memory");
}

// K-tile kt -> global element offsets into Wb (contiguous k) and xT
__device__ __forceinline__ void koffs(int kt, int& ka, int& kb) {
  const int pos = kt >> 2;
  const int cq = kt & 3;
  const int kh = pos / 9;
  const int kw = pos - kh * 9;
  ka = kt * 64;
  kb = kh * XT_HSTRIDE + (kw & 1) * 9216 + (kw >> 1) * 256 + cq * 64;
}

// ---- pack weights: Wb[m][pos*256+c] = bf16(W[m][c][kh][kw]) ----
__global__ __launch_bounds__(256) void pack_w(const float* __restrict__ W,
                                              u16* __restrict__ Wb) {
  __shared__ u16 wl[20736];
  const int m = blockIdx.x;
  const int t = threadIdx.x;
  const size_t base = (size_t)m * K_TOT;
  for (int i = t; i < K_TOT; i += 256) {
    float f = W[base + i];          // input layout per m: (c, pos), i = c*81+pos
    int c = i / 81;
    int pos = i - c * 81;
    wl[pos * 256 + c] = f2bf(f);
  }
  __syncthreads();
  for (int i = t; i < K_TOT; i += 256) Wb[base + i] = wl[i];
}

// ---- pack x: xT[b][h][par][j][c] = bf16(x[b][c][h][2j+par]) ----
__global__ __launch_bounds__(256) void pack_x(const float* __restrict__ X,
                                              u16* __restrict__ xT) {
  __shared__ u16 xl[256 * 73];
  const int h = blockIdx.x;   // 0..70
  const int b = blockIdx.y;   // 0..31
  const int t = threadIdx.x;  // = c on write phase
  for (int i = t; i < 256 * 71; i += 256) {
    int c = i / 71;
    int w = i - c * 71;
    float f = X[(((size_t)(b * 256 + c)) * 71 + h) * 71 + w];
    xl[c * 73 + w] = f2bf(f);
  }
  __syncthreads();
  const size_t obase = (size_t)b * XT_BSTRIDE + (size_t)h * XT_HSTRIDE;
  for (int s = 0; s < 71; ++s) {
    int par = (s >= 36) ? 1 : 0;
    int j = s - par * 36;
    int w = 2 * j + par;
    xT[obase + par * 9216 + j * 256 + t] = xl[t * 73 + w];
  }
}

// ---- conv as implicit GEMM, 256x256 tile, 8-wave 4-phase pipelined ----
// U[m][n] = sum_k Wb[m][k] * X[n][k]; n = b*1024 + hp*32 + wp; k = pos*256 + c
// LDS: double-buffered A/B K-tiles [256][64] bf16, chunk-XOR swizzle
// (phys 16B-chunk p at row r holds logical chunk p ^ (r&7); staged via
// global_load_lds with the inverse permutation on the per-lane SOURCE addr).
// Pipeline: stage tile kt+1 interleaved with compute of tile kt (2 gl_lds per
// phase); vmcnt drains only at next iteration entry -> loads in flight across
// the whole compute iteration (T3/T4). setprio(1) around MFMA clusters (T5).
__global__ __launch_bounds__(512, 2) void conv_gemm(const u16* __restrict__ Wb,
                                                    const u16* __restrict__ xT,
                                                    u16* __restrict__ U) {
  __shared__ __align__(16) u16 As[2][256 * 64];
  __shared__ __align__(16) u16 Bs[2][256 * 64];
  const int tid = threadIdx.x;
  const int bx = blockIdx.x;
  // bijective XCD swizzle: 512 blocks = 8 XCDs x 64; each XCD gets 16
  // consecutive n-tiles x all 4 m-tiles -> B panels shared in its private L2.
  const int swz = (bx & 7) * 64 + (bx >> 3);
  const int m0 = (swz & 3) * 256;
  const int n0 = (swz >> 2) * 256;
  const int lane = tid & 63;
  const int wave = tid >> 6;   // 0..7
  const int wm = wave >> 2;    // 0..1  (M half: rows wm*128..+127)
  const int wn = wave & 3;     // 0..3  (N quarter: rows wn*64..+63)

  // staging: issue (op,q): wave covers rows q*64 + wave*8 .. +7 (1024B linear)
  const int rl = lane >> 3;              // row within 8
  const int gch = (lane & 7) ^ rl;       // pre-swizzled source 16B-chunk

  const u16* aP[4];
  const u16* bP[4];
#pragma unroll
  for (int q = 0; q < 4; ++q) {
    const int row = q * 64 + wave * 8 + rl;
    aP[q] = Wb + (size_t)(m0 + row) * K_TOT + gch * 8;
    const int n = n0 + row;
    const size_t nb = (size_t)(n >> 10) * XT_BSTRIDE +
                      (size_t)(((n >> 5) & 31) * 2) * XT_HSTRIDE +
                      (size_t)(n & 31) * 256;
    bP[q] = xT + nb + gch * 8;
  }
  const int sdst = wave * 8 * 64;        // LDS elem offset of this wave's rows in a q-block

  f32x4 acc[8][4];
#pragma unroll
  for (int i = 0; i < 8; ++i)
#pragma unroll
    for (int j = 0; j < 4; ++j) acc[i][j] = (f32x4){0.f, 0.f, 0.f, 0.f};

  const int fr = lane & 15;      // fragment row
  const int q4 = lane >> 4;      // 8-elem quad within K=32

  // prologue: stage tile 0 into buf 0
  {
    int ka0, kb0;
    koffs(0, ka0, kb0);
#pragma unroll
    for (int q = 0; q < 4; ++q) {
      gl_lds16(aP[q] + ka0, &As[0][q * 64 * 64 + sdst]);
      gl_lds16(bP[q] + kb0, &Bs[0][q * 64 * 64 + sdst]);
    }
  }

#pragma unroll 1
  for (int kt = 0; kt < NKT; ++kt) {
    const int p = kt & 1;
    const bool more = (kt + 1 < NKT);
    int kan = 0, kbn = 0;
    if (more) koffs(kt + 1, kan, kbn);

    // tile kt's loads (issued during previous iteration's phases) done
    asm volatile("s_waitcnt vmcnt(0)" ::: "memory");
    wg_barrier();   // all waves: buf[p] ready; all reads of buf[p^1] finished

#pragma unroll
    for (int kk = 0; kk < 2; ++kk) {
#pragma unroll
      for (int Mh = 0; Mh < 2; ++Mh) {
        const int coff = ((kk * 4 + q4) ^ (fr & 7)) * 8;   // swizzled 16B chunk
        short8 a[4], b[4];
#pragma unroll
        for (int i = 0; i < 4; ++i)
          a[i] = *(const short8*)&As[p][(wm * 128 + Mh * 64 + i * 16 + fr) * 64 + coff];
#pragma unroll
        for (int j = 0; j < 4; ++j)
          b[j] = *(const short8*)&Bs[p][(wn * 64 + j * 16 + fr) * 64 + coff];

        // stage 2 pieces of tile kt+1 into buf[p^1] (fire-and-forget)
        const int ph = kk * 2 + Mh;
        if (more) {
          if (ph < 2) {
            gl_lds16(aP[ph * 2]     + kan, &As[p ^ 1][(ph * 2)     * 64 * 64 + sdst]);
            gl_lds16(aP[ph * 2 + 1] + kan, &As[p ^ 1][(ph * 2 + 1) * 64 * 64 + sdst]);
          } else {
            const int qq = ph - 2;
            gl_lds16(bP[qq * 2]     + kbn, &Bs[p ^ 1][(qq * 2)     * 64 * 64 + sdst]);
            gl_lds16(bP[qq * 2 + 1] + kbn, &Bs[p ^ 1][(qq * 2 + 1) * 64 * 64 + sdst]);
          }
        }

        wg_barrier();   // lockstep: all waves issued reads+stages for this phase
        __builtin_amdgcn_s_setprio(1);
#pragma unroll
        for (int i = 0; i < 4; ++i)
#pragma unroll
          for (int j = 0; j < 4; ++j)
            acc[Mh * 4 + i][j] =
                __builtin_amdgcn_mfma_f32_16x16x32_bf16(a[i], b[j], acc[Mh * 4 + i][j], 0, 0, 0);
        __builtin_amdgcn_s_setprio(0);
      }
    }
  }

  // C/D layout: col = lane&15, row = (lane>>4)*4 + reg   [measured m89/m91]
  const int r0 = (lane >> 4) * 4;
  const int cn = lane & 15;
#pragma unroll
  for (int mi = 0; mi < 8; ++mi) {
#pragma unroll
    for (int j = 0; j < 4; ++j) {
      const int mg = m0 + wm * 128 + mi * 16 + r0;
      const int ng = n0 + wn * 64 + j * 16 + cn;
#pragma unroll
      for (int r = 0; r < 4; ++r)
        U[(size_t)(mg + r) * N_TOT + ng] = f2bf(acc[mi][j][r]);
    }
  }
}

// ---- dynamic routing: one block per (b,hp); thread = (nc,oc) ----
__global__ __launch_bounds__(1024) void routing_k(const u16* __restrict__ U,
                                                  const float* __restrict__ bias,
                                                  float* __restrict__ out) {
  const int t = threadIdx.x;       // m = nc*32 + oc
  const int bx = blockIdx.x;
  const int b = bx >> 5;
  const int hp = bx & 31;
  const int oc = t & 31;
  const int nc = t >> 5;
  __shared__ float sm[1024];

  float u_r[32];
  {
    const uint4* up4 = (const uint4*)(U + (size_t)t * N_TOT + b * 1024 + hp * 32);
    const float bs = bias[t];
#pragma unroll
    for (int i = 0; i < 4; ++i) {
      uint4 q = up4[i];
      uint32_t vv[4] = {q.x, q.y, q.z, q.w};
#pragma unroll
      for (int k = 0; k < 4; ++k) {
        u_r[i * 8 + k * 2]     = bf2f((u16)(vv[k] & 0xffffu)) + bs;
        u_r[i * 8 + k * 2 + 1] = bf2f((u16)(vv[k] >> 16)) + bs;
      }
    }
  }

  float bij = 0.f;
  float s[32];
  float scale = 0.f;

  for (int it = 0; it < 3; ++it) {
    sm[t] = bij;
    __syncthreads();
    // softmax over nc for this oc (values are small; no max-subtract needed)
    float den = 0.f;
#pragma unroll
    for (int i = 0; i < 32; ++i) den += __expf(sm[i * 32 + oc]);
    const float c = __expf(bij) / den;
    // s[nc][wp] = sum_oc c*u_hat : butterfly allreduce across the 32-lane oc group
#pragma unroll
    for (int w = 0; w < 32; ++w) s[w] = c * u_r[w];
#pragma unroll
    for (int off = 1; off < 32; off <<= 1) {
#pragma unroll
      for (int w = 0; w < 32; ++w) s[w] += __shfl_xor(s[w], off, 64);
    }
    // squash over wp
    float n2 = 0.f;
#pragma unroll
    for (int w = 0; w < 32; ++w) n2 += s[w] * s[w];
    scale = sqrtf(n2) / (1.f + n2);
    if (it < 2) {
      // b_ij += sum_wp u_hat * v ;  v = scale*s
      float agr = 0.f;
#pragma unroll
      for (int w = 0; w < 32; ++w) agr += u_r[w] * s[w];
      bij += scale * agr;
    }
    __syncthreads();
  }

  // lane oc writes element wp==oc (register-select to avoid scratch)
  float val = s[0];
#pragma unroll
  for (int i = 1; i < 32; ++i) val = (oc == i) ? s[i] : val;
  out[(size_t)((b * 32 + nc) * 32 + hp) * 32 + oc] = scale * val;
}

extern "C" void kernel_launch(void* const* d_in, const int* in_sizes, int n_in,
                              void* d_out, int out_size, void* d_ws, size_t ws_size,
                              hipStream_t stream) {
  const float* x = (const float*)d_in[0];
  const float* W = (const float*)d_in[1];
  const float* bias = (const float*)d_in[2];

  // workspace layout (bytes): Wb 42,467,328 | xT 83,755,008 | U 67,108,864  (total 193.3 MB)
  u16* Wb = (u16*)d_ws;
  u16* xT = (u16*)((char*)d_ws + 42467328u);
  u16* U  = (u16*)((char*)d_ws + 126222336u);
  float* out = (float*)d_out;

  pack_w<<<dim3(1024), dim3(256), 0, stream>>>(W, Wb);
  pack_x<<<dim3(71, 32), dim3(256), 0, stream>>>(x, xT);
  conv_gemm<<<dim3(512), dim3(512), 0, stream>>>(Wb, xT, U);
  routing_k<<<dim3(1024), dim3(1024), 0, stream>>>(U, bias, out);
}

// Round 3
// 1569.002 us; speedup vs baseline: 1.4663x; 1.0243x over previous
//
#include <hip/hip_runtime.h>
#include <cstdint>
#include <cstddef>

typedef unsigned short u16;
typedef __attribute__((ext_vector_type(8))) short short8;
typedef __attribute__((ext_vector_type(4))) float f32x4;

#define XT_HSTRIDE 18432      /* 2*36*256 */
#define XT_BSTRIDE 1308672    /* 71*18432 */
#define K_TOT 20736
#define N_TOT 32768
#define NKT 324               /* K-tiles of 64: 81 pos * 4 */

__device__ __forceinline__ u16 f2bf(float f) {
  uint32_t u = __builtin_bit_cast(uint32_t, f);
  u = (u + 0x7fffu + ((u >> 16) & 1u)) >> 16;
  return (u16)u;
}
__device__ __forceinline__ float bf2f(u16 h) {
  uint32_t u = ((uint32_t)h) << 16;
  return __builtin_bit_cast(float, u);
}

// async global->LDS, 16B per lane; LDS dest is wave-uniform base + lane*16
__device__ __forceinline__ void gl_lds16(const u16* g, u16* l) {
  __builtin_amdgcn_global_load_lds((const __attribute__((address_space(1))) void*)g,
                                   (__attribute__((address_space(3))) void*)l, 16, 0, 0);
}

__device__ __forceinline__ void wg_barrier() {
  asm volatile("" ::: "memory");
  __builtin_amdgcn_s_barrier();
  asm volatile("" ::: "memory");
}

// K-tile kt -> global element offsets into Wb (contiguous k) and xT
__device__ __forceinline__ void koffs(int kt, int& ka, int& kb) {
  const int pos = kt >> 2;
  const int cq = kt & 3;
  const int kh = pos / 9;
  const int kw = pos - kh * 9;
  ka = kt * 64;
  kb = kh * XT_HSTRIDE + (kw & 1) * 9216 + (kw >> 1) * 256 + cq * 64;
}

// ---- pack weights: Wb[m][pos*256+c] = bf16(W[m][c][kh][kw]) ----
__global__ __launch_bounds__(256) void pack_w(const float* __restrict__ W,
                                              u16* __restrict__ Wb) {
  __shared__ u16 wl[20736];
  const int m = blockIdx.x;
  const int t = threadIdx.x;
  const size_t base = (size_t)m * K_TOT;
  for (int i = t; i < K_TOT; i += 256) {
    float f = W[base + i];          // input layout per m: (c, pos), i = c*81+pos
    int c = i / 81;
    int pos = i - c * 81;
    wl[pos * 256 + c] = f2bf(f);
  }
  __syncthreads();
  for (int i = t; i < K_TOT; i += 256) Wb[base + i] = wl[i];
}

// ---- pack x: xT[b][h][par][j][c] = bf16(x[b][c][h][2j+par]) ----
__global__ __launch_bounds__(256) void pack_x(const float* __restrict__ X,
                                              u16* __restrict__ xT) {
  __shared__ u16 xl[256 * 73];
  const int h = blockIdx.x;   // 0..70
  const int b = blockIdx.y;   // 0..31
  const int t = threadIdx.x;  // = c on write phase
  for (int i = t; i < 256 * 71; i += 256) {
    int c = i / 71;
    int w = i - c * 71;
    float f = X[(((size_t)(b * 256 + c)) * 71 + h) * 71 + w];
    xl[c * 73 + w] = f2bf(f);
  }
  __syncthreads();
  const size_t obase = (size_t)b * XT_BSTRIDE + (size_t)h * XT_HSTRIDE;
  for (int s = 0; s < 71; ++s) {
    int par = (s >= 36) ? 1 : 0;
    int j = s - par * 36;
    int w = 2 * j + par;
    xT[obase + par * 9216 + j * 256 + t] = xl[t * 73 + w];
  }
}

// ---- conv as implicit GEMM, 256x256 tile, 8-wave, counted-vmcnt pipeline ----
// U[m][n] = sum_k Wb[m][k] * X[n][k]; n = b*1024 + hp*32 + wp; k = pos*256 + c
// LDS: double-buffered A/B K-tiles [256][64] bf16, chunk-XOR swizzle (phys 16B
// chunk p at row r holds logical chunk p ^ (r&7)); staged via global_load_lds
// with the inverse permutation on the per-lane SOURCE address (rule 21).
// Phase order (Mh outer, kk inner); per-wave staging issue order for tile kt+1:
//   P0: B0,B1   P1: B2,B3   P2: A0,A2   P3: A1,A3
// so entry needs only the oldest 6 (vmcnt(2)) and mid-iteration needs A1,A3
// (vmcnt(4)). vmcnt never drains to 0 in the steady-state loop (T4); every
// awaited load has >=2 phases of MFMA cover. setprio around MFMA (T5).
__global__ __launch_bounds__(512, 2) void conv_gemm(const u16* __restrict__ Wb,
                                                    const u16* __restrict__ xT,
                                                    u16* __restrict__ U) {
  __shared__ __align__(16) u16 As[2][256 * 64];
  __shared__ __align__(16) u16 Bs[2][256 * 64];
  const int tid = threadIdx.x;
  const int bx = blockIdx.x;
  // bijective XCD swizzle: 512 blocks = 8 XCDs x 64; each XCD gets 16
  // consecutive n-tiles x all 4 m-tiles -> B panels shared in its private L2.
  const int swz = (bx & 7) * 64 + (bx >> 3);
  const int m0 = (swz & 3) * 256;
  const int n0 = (swz >> 2) * 256;
  const int lane = tid & 63;
  const int wave = tid >> 6;   // 0..7
  const int wm = wave >> 2;    // 0..1  (M half: rows wm*128..+127)
  const int wn = wave & 3;     // 0..3  (N quarter: rows wn*64..+63)

  // staging: issue (op,q): wave covers rows q*64 + wave*8 .. +7 (1024B linear)
  const int rl = lane >> 3;              // row within 8
  const int gch = (lane & 7) ^ rl;       // pre-swizzled source 16B-chunk

  const u16* aP[4];
  const u16* bP[4];
#pragma unroll
  for (int q = 0; q < 4; ++q) {
    const int row = q * 64 + wave * 8 + rl;
    aP[q] = Wb + (size_t)(m0 + row) * K_TOT + gch * 8;
    const int n = n0 + row;
    const size_t nb = (size_t)(n >> 10) * XT_BSTRIDE +
                      (size_t)(((n >> 5) & 31) * 2) * XT_HSTRIDE +
                      (size_t)(n & 31) * 256;
    bP[q] = xT + nb + gch * 8;
  }
  const int sdst = wave * 8 * 64;        // LDS elem offset of this wave's rows in a q-block

  f32x4 acc[8][4];
#pragma unroll
  for (int i = 0; i < 8; ++i)
#pragma unroll
    for (int j = 0; j < 4; ++j) acc[i][j] = (f32x4){0.f, 0.f, 0.f, 0.f};

  const int fr = lane & 15;      // fragment row
  const int q4 = lane >> 4;      // 8-elem quad within K=32
  const int coff0 = ((q4) ^ (fr & 7)) * 8;        // swizzled chunk, kk=0
  const int coff1 = ((4 + q4) ^ (fr & 7)) * 8;    // swizzled chunk, kk=1

  // prologue: stage tile 0 into buf 0, canonical issue order B0..B3,A0,A2,A1,A3
  {
    int ka0, kb0;
    koffs(0, ka0, kb0);
    gl_lds16(bP[0] + kb0, &Bs[0][0 * 4096 + sdst]);
    gl_lds16(bP[1] + kb0, &Bs[0][1 * 4096 + sdst]);
    gl_lds16(bP[2] + kb0, &Bs[0][2 * 4096 + sdst]);
    gl_lds16(bP[3] + kb0, &Bs[0][3 * 4096 + sdst]);
    gl_lds16(aP[0] + ka0, &As[0][0 * 4096 + sdst]);
    gl_lds16(aP[2] + ka0, &As[0][2 * 4096 + sdst]);
    gl_lds16(aP[1] + ka0, &As[0][1 * 4096 + sdst]);
    gl_lds16(aP[3] + ka0, &As[0][3 * 4096 + sdst]);
  }

#pragma unroll 1
  for (int kt = 0; kt < NKT; ++kt) {
    const int p = kt & 1;
    const bool more = (kt + 1 < NKT);
    int kan = 0, kbn = 0;
    if (more) koffs(kt + 1, kan, kbn);
    u16* An = &As[p ^ 1][0];
    u16* Bn = &Bs[p ^ 1][0];

    // entry: B*, A0, A2 of tile kt ready (oldest 6); A1,A3 may still fly
    asm volatile("s_waitcnt vmcnt(2)" ::: "memory");
    wg_barrier();

    short8 bq0[4], bq1[4];   // B fragments kk=0/1, reused across both M-halves

    // ---- P0: (Mh=0, kk=0) ----
    {
      short8 a[4];
#pragma unroll
      for (int i = 0; i < 4; ++i)
        a[i] = *(const short8*)&As[p][(wm * 128 + i * 16 + fr) * 64 + coff0];
#pragma unroll
      for (int j = 0; j < 4; ++j)
        bq0[j] = *(const short8*)&Bs[p][(wn * 64 + j * 16 + fr) * 64 + coff0];
      if (more) {
        gl_lds16(bP[0] + kbn, Bn + 0 * 4096 + sdst);
        gl_lds16(bP[1] + kbn, Bn + 1 * 4096 + sdst);
      }
      wg_barrier();
      __builtin_amdgcn_s_setprio(1);
#pragma unroll
      for (int i = 0; i < 4; ++i)
#pragma unroll
        for (int j = 0; j < 4; ++j)
          acc[i][j] = __builtin_amdgcn_mfma_f32_16x16x32_bf16(a[i], bq0[j], acc[i][j], 0, 0, 0);
      __builtin_amdgcn_s_setprio(0);
    }

    // ---- P1: (Mh=0, kk=1) ----
    {
      short8 a[4];
#pragma unroll
      for (int i = 0; i < 4; ++i)
        a[i] = *(const short8*)&As[p][(wm * 128 + i * 16 + fr) * 64 + coff1];
#pragma unroll
      for (int j = 0; j < 4; ++j)
        bq1[j] = *(const short8*)&Bs[p][(wn * 64 + j * 16 + fr) * 64 + coff1];
      if (more) {
        gl_lds16(bP[2] + kbn, Bn + 2 * 4096 + sdst);
        gl_lds16(bP[3] + kbn, Bn + 3 * 4096 + sdst);
        // A1,A3 of tile kt (last 2 of prev iter's issues) must land before P2.
        // outstanding: [A1,A3 old][B0..B3 new] = 6 -> wait oldest 2.
        asm volatile("s_waitcnt vmcnt(4)" ::: "memory");
      } else {
        asm volatile("s_waitcnt vmcnt(0)" ::: "memory");
      }
      wg_barrier();
      __builtin_amdgcn_s_setprio(1);
#pragma unroll
      for (int i = 0; i < 4; ++i)
#pragma unroll
        for (int j = 0; j < 4; ++j)
          acc[i][j] = __builtin_amdgcn_mfma_f32_16x16x32_bf16(a[i], bq1[j], acc[i][j], 0, 0, 0);
      __builtin_amdgcn_s_setprio(0);
    }

    // ---- P2: (Mh=1, kk=0) ----
    {
      short8 a[4];
#pragma unroll
      for (int i = 0; i < 4; ++i)
        a[i] = *(const short8*)&As[p][(wm * 128 + 64 + i * 16 + fr) * 64 + coff0];
      if (more) {
        gl_lds16(aP[0] + kan, An + 0 * 4096 + sdst);
        gl_lds16(aP[2] + kan, An + 2 * 4096 + sdst);
      }
      wg_barrier();
      __builtin_amdgcn_s_setprio(1);
#pragma unroll
      for (int i = 0; i < 4; ++i)
#pragma unroll
        for (int j = 0; j < 4; ++j)
          acc[4 + i][j] = __builtin_amdgcn_mfma_f32_16x16x32_bf16(a[i], bq0[j], acc[4 + i][j], 0, 0, 0);
      __builtin_amdgcn_s_setprio(0);
    }

    // ---- P3: (Mh=1, kk=1) ----
    {
      short8 a[4];
#pragma unroll
      for (int i = 0; i < 4; ++i)
        a[i] = *(const short8*)&As[p][(wm * 128 + 64 + i * 16 + fr) * 64 + coff1];
      if (more) {
        gl_lds16(aP[1] + kan, An + 1 * 4096 + sdst);
        gl_lds16(aP[3] + kan, An + 3 * 4096 + sdst);
      }
      wg_barrier();
      __builtin_amdgcn_s_setprio(1);
#pragma unroll
      for (int i = 0; i < 4; ++i)
#pragma unroll
        for (int j = 0; j < 4; ++j)
          acc[4 + i][j] = __builtin_amdgcn_mfma_f32_16x16x32_bf16(a[i], bq1[j], acc[4 + i][j], 0, 0, 0);
      __builtin_amdgcn_s_setprio(0);
    }
  }

  // C/D layout: col = lane&15, row = (lane>>4)*4 + reg   [measured m89/m91]
  const int r0 = (lane >> 4) * 4;
  const int cn = lane & 15;
#pragma unroll
  for (int mi = 0; mi < 8; ++mi) {
#pragma unroll
    for (int j = 0; j < 4; ++j) {
      const int mg = m0 + wm * 128 + ((mi & 3) * 16) + ((mi >> 2) * 64) + r0;
      const int ng = n0 + wn * 64 + j * 16 + cn;
#pragma unroll
      for (int r = 0; r < 4; ++r)
        U[(size_t)(mg + r) * N_TOT + ng] = f2bf(acc[mi][j][r]);
    }
  }
}

// ---- dynamic routing: one block per (b,hp); thread = (nc,oc) ----
__global__ __launch_bounds__(1024) void routing_k(const u16* __restrict__ U,
                                                  const float* __restrict__ bias,
                                                  float* __restrict__ out) {
  const int t = threadIdx.x;       // m = nc*32 + oc
  const int bx = blockIdx.x;
  const int b = bx >> 5;
  const int hp = bx & 31;
  const int oc = t & 31;
  const int nc = t >> 5;
  __shared__ float sm[1024];

  float u_r[32];
  {
    const uint4* up4 = (const uint4*)(U + (size_t)t * N_TOT + b * 1024 + hp * 32);
    const float bs = bias[t];
#pragma unroll
    for (int i = 0; i < 4; ++i) {
      uint4 q = up4[i];
      uint32_t vv[4] = {q.x, q.y, q.z, q.w};
#pragma unroll
      for (int k = 0; k < 4; ++k) {
        u_r[i * 8 + k * 2]     = bf2f((u16)(vv[k] & 0xffffu)) + bs;
        u_r[i * 8 + k * 2 + 1] = bf2f((u16)(vv[k] >> 16)) + bs;
      }
    }
  }

  float bij = 0.f;
  float s[32];
  float scale = 0.f;

  for (int it = 0; it < 3; ++it) {
    sm[t] = bij;
    __syncthreads();
    // softmax over nc for this oc (values are small; no max-subtract needed)
    float den = 0.f;
#pragma unroll
    for (int i = 0; i < 32; ++i) den += __expf(sm[i * 32 + oc]);
    const float c = __expf(bij) / den;
    // s[nc][wp] = sum_oc c*u_hat : butterfly allreduce across the 32-lane oc group
#pragma unroll
    for (int w = 0; w < 32; ++w) s[w] = c * u_r[w];
#pragma unroll
    for (int off = 1; off < 32; off <<= 1) {
#pragma unroll
      for (int w = 0; w < 32; ++w) s[w] += __shfl_xor(s[w], off, 64);
    }
    // squash over wp
    float n2 = 0.f;
#pragma unroll
    for (int w = 0; w < 32; ++w) n2 += s[w] * s[w];
    scale = sqrtf(n2) / (1.f + n2);
    if (it < 2) {
      // b_ij += sum_wp u_hat * v ;  v = scale*s
      float agr = 0.f;
#pragma unroll
      for (int w = 0; w < 32; ++w) agr += u_r[w] * s[w];
      bij += scale * agr;
    }
    __syncthreads();
  }

  // lane oc writes element wp==oc (register-select to avoid scratch)
  float val = s[0];
#pragma unroll
  for (int i = 1; i < 32; ++i) val = (oc == i) ? s[i] : val;
  out[(size_t)((b * 32 + nc) * 32 + hp) * 32 + oc] = scale * val;
}

extern "C" void kernel_launch(void* const* d_in, const int* in_sizes, int n_in,
                              void* d_out, int out_size, void* d_ws, size_t ws_size,
                              hipStream_t stream) {
  const float* x = (const float*)d_in[0];
  const float* W = (const float*)d_in[1];
  const float* bias = (const float*)d_in[2];

  // workspace layout (bytes): Wb 42,467,328 | xT 83,755,008 | U 67,108,864  (total 193.3 MB)
  u16* Wb = (u16*)d_ws;
  u16* xT = (u16*)((char*)d_ws + 42467328u);
  u16* U  = (u16*)((char*)d_ws + 126222336u);
  float* out = (float*)d_out;

  pack_w<<<dim3(1024), dim3(256), 0, stream>>>(W, Wb);
  pack_x<<<dim3(71, 32), dim3(256), 0, stream>>>(x, xT);
  conv_gemm<<<dim3(512), dim3(512), 0, stream>>>(Wb, xT, U);
  routing_k<<<dim3(1024), dim3(1024), 0, stream>>>(U, bias, out);
}

// Round 4
// 1535.073 us; speedup vs baseline: 1.4987x; 1.0221x over previous
//
#include <hip/hip_runtime.h>
#include <cstdint>
#include <cstddef>

typedef unsigned short u16;
typedef __attribute__((ext_vector_type(8))) short short8;
typedef __attribute__((ext_vector_type(4))) float f32x4;

#define XT_HSTRIDE 18432      /* 2*36*256 */
#define XT_BSTRIDE 1308672    /* 71*18432 */
#define K_TOT 20736
#define N_TOT 32768
#define NKT 324               /* K-tiles of 64: 81 pos * 4 */

__device__ __forceinline__ u16 f2bf(float f) {
  uint32_t u = __builtin_bit_cast(uint32_t, f);
  u = (u + 0x7fffu + ((u >> 16) & 1u)) >> 16;
  return (u16)u;
}
__device__ __forceinline__ float bf2f(u16 h) {
  uint32_t u = ((uint32_t)h) << 16;
  return __builtin_bit_cast(float, u);
}

// async global->LDS, 16B per lane; LDS dest is wave-uniform base + lane*16
__device__ __forceinline__ void gl_lds16(const u16* g, u16* l) {
  __builtin_amdgcn_global_load_lds((const __attribute__((address_space(1))) void*)g,
                                   (__attribute__((address_space(3))) void*)l, 16, 0, 0);
}

__device__ __forceinline__ void wg_barrier() {
  asm volatile("" ::: "memory");
  __builtin_amdgcn_s_barrier();
  asm volatile("" ::: "memory");
}

// K-tile kt -> global element offsets into Wb (contiguous k) and xT
__device__ __forceinline__ void koffs(int kt, int& ka, int& kb) {
  const int pos = kt >> 2;
  const int cq = kt & 3;
  const int kh = pos / 9;
  const int kw = pos - kh * 9;
  ka = kt * 64;
  kb = kh * XT_HSTRIDE + (kw & 1) * 9216 + (kw >> 1) * 256 + cq * 64;
}

// ---- pack weights: Wb[m][pos*256+c] = bf16(W[m][c][kh][kw]) ----
__global__ __launch_bounds__(256) void pack_w(const float* __restrict__ W,
                                              u16* __restrict__ Wb) {
  __shared__ u16 wl[20736];
  const int m = blockIdx.x;
  const int t = threadIdx.x;
  const size_t base = (size_t)m * K_TOT;
  for (int i = t; i < K_TOT; i += 256) {
    float f = W[base + i];          // input layout per m: (c, pos), i = c*81+pos
    int c = i / 81;
    int pos = i - c * 81;
    wl[pos * 256 + c] = f2bf(f);
  }
  __syncthreads();
  for (int i = t; i < K_TOT; i += 256) Wb[base + i] = wl[i];
}

// ---- pack x: xT[b][h][par][j][c] = bf16(x[b][c][h][2j+par]) ----
__global__ __launch_bounds__(256) void pack_x(const float* __restrict__ X,
                                              u16* __restrict__ xT) {
  __shared__ u16 xl[256 * 73];
  const int h = blockIdx.x;   // 0..70
  const int b = blockIdx.y;   // 0..31
  const int t = threadIdx.x;  // = c on write phase
  for (int i = t; i < 256 * 71; i += 256) {
    int c = i / 71;
    int w = i - c * 71;
    float f = X[(((size_t)(b * 256 + c)) * 71 + h) * 71 + w];
    xl[c * 73 + w] = f2bf(f);
  }
  __syncthreads();
  const size_t obase = (size_t)b * XT_BSTRIDE + (size_t)h * XT_HSTRIDE;
  for (int s = 0; s < 71; ++s) {
    int par = (s >= 36) ? 1 : 0;
    int j = s - par * 36;
    int w = 2 * j + par;
    xT[obase + par * 9216 + j * 256 + t] = xl[t * 73 + w];
  }
}

// ---- conv as implicit GEMM, 256x256 tile, 8-wave, 1-barrier/tile pipeline ----
// U[m][n] = sum_k Wb[m][k] * X[n][k]; n = b*1024 + hp*32 + wp; k = pos*256 + c
// LDS: double-buffered A/B K-tiles [256][64] bf16, chunk-XOR swizzle (phys 16B
// chunk p at row r holds logical chunk p ^ (r&7)); staged via global_load_lds
// with the inverse permutation on the per-lane SOURCE address (rule 21).
// Sync: ONE {vmcnt(0); barrier} per K-tile. Safe because (a) each wave's 8
// staging loads for tile kt were issued during tile kt-1 (a full tile of
// cover), so vmcnt(0)+barrier makes buf[p] visible to all waves before any
// read; (b) a wave arrives at the barrier only after its lgkm-waited reads of
// buf[p^1] completed, so restaging buf[p^1] during tile kt is race-free;
// (c) gl_lds destination rows are per-wave disjoint. Within the tile waves
// free-run: fragment reads front-loaded, MFMA clusters gated by
// compiler-counted lgkmcnt, sched_barrier(0) pinning cluster boundaries,
// setprio(1) around MFMA (T5). LDS pipe and MFMA pipe overlap via wave drift.
__global__ __launch_bounds__(512, 2) void conv_gemm(const u16* __restrict__ Wb,
                                                    const u16* __restrict__ xT,
                                                    u16* __restrict__ U) {
  __shared__ __align__(16) u16 As[2][256 * 64];
  __shared__ __align__(16) u16 Bs[2][256 * 64];
  const int tid = threadIdx.x;
  const int bx = blockIdx.x;
  // bijective XCD swizzle: 512 blocks = 8 XCDs x 64; each XCD gets 16
  // consecutive n-tiles x all 4 m-tiles -> B panels shared in its private L2.
  const int swz = (bx & 7) * 64 + (bx >> 3);
  const int m0 = (swz & 3) * 256;
  const int n0 = (swz >> 2) * 256;
  const int lane = tid & 63;
  const int wave = tid >> 6;   // 0..7
  const int wm = wave >> 2;    // 0..1  (M half: rows wm*128..+127)
  const int wn = wave & 3;     // 0..3  (N quarter: rows wn*64..+63)

  // staging: issue (op,q): wave covers rows q*64 + wave*8 .. +7 (1024B linear)
  const int rl = lane >> 3;              // row within 8
  const int gch = (lane & 7) ^ rl;       // pre-swizzled source 16B-chunk

  const u16* aP[4];
  const u16* bP[4];
#pragma unroll
  for (int q = 0; q < 4; ++q) {
    const int row = q * 64 + wave * 8 + rl;
    aP[q] = Wb + (size_t)(m0 + row) * K_TOT + gch * 8;
    const int n = n0 + row;
    const size_t nb = (size_t)(n >> 10) * XT_BSTRIDE +
                      (size_t)(((n >> 5) & 31) * 2) * XT_HSTRIDE +
                      (size_t)(n & 31) * 256;
    bP[q] = xT + nb + gch * 8;
  }
  const int sdst = wave * 8 * 64;        // LDS elem offset of this wave's rows in a q-block

  f32x4 acc[8][4];
#pragma unroll
  for (int i = 0; i < 8; ++i)
#pragma unroll
    for (int j = 0; j < 4; ++j) acc[i][j] = (f32x4){0.f, 0.f, 0.f, 0.f};

  const int fr = lane & 15;      // fragment row
  const int q4 = lane >> 4;      // 8-elem quad within K=32
  const int coff0 = ((q4) ^ (fr & 7)) * 8;        // swizzled chunk, kk=0
  const int coff1 = ((4 + q4) ^ (fr & 7)) * 8;    // swizzled chunk, kk=1

  // prologue: stage tile 0 into buf 0
  {
    int ka0, kb0;
    koffs(0, ka0, kb0);
    gl_lds16(bP[0] + kb0, &Bs[0][0 * 4096 + sdst]);
    gl_lds16(bP[1] + kb0, &Bs[0][1 * 4096 + sdst]);
    gl_lds16(bP[2] + kb0, &Bs[0][2 * 4096 + sdst]);
    gl_lds16(bP[3] + kb0, &Bs[0][3 * 4096 + sdst]);
    gl_lds16(aP[0] + ka0, &As[0][0 * 4096 + sdst]);
    gl_lds16(aP[1] + ka0, &As[0][1 * 4096 + sdst]);
    gl_lds16(aP[2] + ka0, &As[0][2 * 4096 + sdst]);
    gl_lds16(aP[3] + ka0, &As[0][3 * 4096 + sdst]);
  }

#pragma unroll 1
  for (int kt = 0; kt < NKT; ++kt) {
    const int p = kt & 1;
    const bool more = (kt + 1 < NKT);
    int kan = 0, kbn = 0;
    if (more) koffs(kt + 1, kan, kbn);
    u16* An = &As[p ^ 1][0];
    u16* Bn = &Bs[p ^ 1][0];
    const u16* Ac = &As[p][0];
    const u16* Bc = &Bs[p][0];

    // single sync point per tile: own staging drained + all waves arrived
    // -> buf[p] fully populated chip-side, buf[p^1] reads all retired.
    asm volatile("s_waitcnt vmcnt(0)" ::: "memory");
    wg_barrier();

    short8 a00[4], a01[4], a10[4], a11[4], bq0[4], bq1[4];

    // front-load Mh0 + B fragments (16 ds_read_b128); LDS pipe starts churning
#pragma unroll
    for (int i = 0; i < 4; ++i) {
      a00[i] = *(const short8*)&Ac[(wm * 128 + i * 16 + fr) * 64 + coff0];
      bq0[i] = *(const short8*)&Bc[(wn * 64 + i * 16 + fr) * 64 + coff0];
      a01[i] = *(const short8*)&Ac[(wm * 128 + i * 16 + fr) * 64 + coff1];
      bq1[i] = *(const short8*)&Bc[(wn * 64 + i * 16 + fr) * 64 + coff1];
    }
    if (more) {
      gl_lds16(bP[0] + kbn, Bn + 0 * 4096 + sdst);
      gl_lds16(bP[1] + kbn, Bn + 1 * 4096 + sdst);
    }
    __builtin_amdgcn_sched_barrier(0);

    // cluster 0: (Mh0, kk0) — needs oldest 8 reads only (compiler counts)
    __builtin_amdgcn_s_setprio(1);
#pragma unroll
    for (int i = 0; i < 4; ++i)
#pragma unroll
      for (int j = 0; j < 4; ++j)
        acc[i][j] = __builtin_amdgcn_mfma_f32_16x16x32_bf16(a00[i], bq0[j], acc[i][j], 0, 0, 0);
    __builtin_amdgcn_s_setprio(0);
    __builtin_amdgcn_sched_barrier(0);

#pragma unroll
    for (int i = 0; i < 4; ++i)
      a10[i] = *(const short8*)&Ac[(wm * 128 + 64 + i * 16 + fr) * 64 + coff0];
    if (more) {
      gl_lds16(bP[2] + kbn, Bn + 2 * 4096 + sdst);
      gl_lds16(bP[3] + kbn, Bn + 3 * 4096 + sdst);
    }
    __builtin_amdgcn_sched_barrier(0);

    // cluster 1: (Mh0, kk1)
    __builtin_amdgcn_s_setprio(1);
#pragma unroll
    for (int i = 0; i < 4; ++i)
#pragma unroll
      for (int j = 0; j < 4; ++j)
        acc[i][j] = __builtin_amdgcn_mfma_f32_16x16x32_bf16(a01[i], bq1[j], acc[i][j], 0, 0, 0);
    __builtin_amdgcn_s_setprio(0);
    __builtin_amdgcn_sched_barrier(0);

#pragma unroll
    for (int i = 0; i < 4; ++i)
      a11[i] = *(const short8*)&Ac[(wm * 128 + 64 + i * 16 + fr) * 64 + coff1];
    if (more) {
      gl_lds16(aP[0] + kan, An + 0 * 4096 + sdst);
      gl_lds16(aP[2] + kan, An + 2 * 4096 + sdst);
    }
    __builtin_amdgcn_sched_barrier(0);

    // cluster 2: (Mh1, kk0)
    __builtin_amdgcn_s_setprio(1);
#pragma unroll
    for (int i = 0; i < 4; ++i)
#pragma unroll
      for (int j = 0; j < 4; ++j)
        acc[4 + i][j] = __builtin_amdgcn_mfma_f32_16x16x32_bf16(a10[i], bq0[j], acc[4 + i][j], 0, 0, 0);
    __builtin_amdgcn_s_setprio(0);
    __builtin_amdgcn_sched_barrier(0);

    if (more) {
      gl_lds16(aP[1] + kan, An + 1 * 4096 + sdst);
      gl_lds16(aP[3] + kan, An + 3 * 4096 + sdst);
    }
    __builtin_amdgcn_sched_barrier(0);

    // cluster 3: (Mh1, kk1)
    __builtin_amdgcn_s_setprio(1);
#pragma unroll
    for (int i = 0; i < 4; ++i)
#pragma unroll
      for (int j = 0; j < 4; ++j)
        acc[4 + i][j] = __builtin_amdgcn_mfma_f32_16x16x32_bf16(a11[i], bq1[j], acc[4 + i][j], 0, 0, 0);
    __builtin_amdgcn_s_setprio(0);
  }

  // C/D layout: col = lane&15, row = (lane>>4)*4 + reg   [measured m89/m91]
  const int r0 = (lane >> 4) * 4;
  const int cn = lane & 15;
#pragma unroll
  for (int mi = 0; mi < 8; ++mi) {
#pragma unroll
    for (int j = 0; j < 4; ++j) {
      const int mg = m0 + wm * 128 + ((mi & 3) * 16) + ((mi >> 2) * 64) + r0;
      const int ng = n0 + wn * 64 + j * 16 + cn;
#pragma unroll
      for (int r = 0; r < 4; ++r)
        U[(size_t)(mg + r) * N_TOT + ng] = f2bf(acc[mi][j][r]);
    }
  }
}

// ---- dynamic routing: one block per (b,hp); thread = (nc,oc) ----
__global__ __launch_bounds__(1024) void routing_k(const u16* __restrict__ U,
                                                  const float* __restrict__ bias,
                                                  float* __restrict__ out) {
  const int t = threadIdx.x;       // m = nc*32 + oc
  const int bx = blockIdx.x;
  const int b = bx >> 5;
  const int hp = bx & 31;
  const int oc = t & 31;
  const int nc = t >> 5;
  __shared__ float sm[1024];

  float u_r[32];
  {
    const uint4* up4 = (const uint4*)(U + (size_t)t * N_TOT + b * 1024 + hp * 32);
    const float bs = bias[t];
#pragma unroll
    for (int i = 0; i < 4; ++i) {
      uint4 q = up4[i];
      uint32_t vv[4] = {q.x, q.y, q.z, q.w};
#pragma unroll
      for (int k = 0; k < 4; ++k) {
        u_r[i * 8 + k * 2]     = bf2f((u16)(vv[k] & 0xffffu)) + bs;
        u_r[i * 8 + k * 2 + 1] = bf2f((u16)(vv[k] >> 16)) + bs;
      }
    }
  }

  float bij = 0.f;
  float s[32];
  float scale = 0.f;

  for (int it = 0; it < 3; ++it) {
    sm[t] = bij;
    __syncthreads();
    // softmax over nc for this oc (values are small; no max-subtract needed)
    float den = 0.f;
#pragma unroll
    for (int i = 0; i < 32; ++i) den += __expf(sm[i * 32 + oc]);
    const float c = __expf(bij) / den;
    // s[nc][wp] = sum_oc c*u_hat : butterfly allreduce across the 32-lane oc group
#pragma unroll
    for (int w = 0; w < 32; ++w) s[w] = c * u_r[w];
#pragma unroll
    for (int off = 1; off < 32; off <<= 1) {
#pragma unroll
      for (int w = 0; w < 32; ++w) s[w] += __shfl_xor(s[w], off, 64);
    }
    // squash over wp
    float n2 = 0.f;
#pragma unroll
    for (int w = 0; w < 32; ++w) n2 += s[w] * s[w];
    scale = sqrtf(n2) / (1.f + n2);
    if (it < 2) {
      // b_ij += sum_wp u_hat * v ;  v = scale*s
      float agr = 0.f;
#pragma unroll
      for (int w = 0; w < 32; ++w) agr += u_r[w] * s[w];
      bij += scale * agr;
    }
    __syncthreads();
  }

  // lane oc writes element wp==oc (register-select to avoid scratch)
  float val = s[0];
#pragma unroll
  for (int i = 1; i < 32; ++i) val = (oc == i) ? s[i] : val;
  out[(size_t)((b * 32 + nc) * 32 + hp) * 32 + oc] = scale * val;
}

extern "C" void kernel_launch(void* const* d_in, const int* in_sizes, int n_in,
                              void* d_out, int out_size, void* d_ws, size_t ws_size,
                              hipStream_t stream) {
  const float* x = (const float*)d_in[0];
  const float* W = (const float*)d_in[1];
  const float* bias = (const float*)d_in[2];

  // workspace layout (bytes): Wb 42,467,328 | xT 83,755,008 | U 67,108,864  (total 193.3 MB)
  u16* Wb = (u16*)d_ws;
  u16* xT = (u16*)((char*)d_ws + 42467328u);
  u16* U  = (u16*)((char*)d_ws + 126222336u);
  float* out = (float*)d_out;

  pack_w<<<dim3(1024), dim3(256), 0, stream>>>(W, Wb);
  pack_x<<<dim3(71, 32), dim3(256), 0, stream>>>(x, xT);
  conv_gemm<<<dim3(512), dim3(512), 0, stream>>>(Wb, xT, U);
  routing_k<<<dim3(1024), dim3(1024), 0, stream>>>(U, bias, out);
}